// Round 9
// baseline (2891.443 us; speedup 1.0000x reference)
//
#include <hip/hip_runtime.h>
#include <stdint.h>

#define TT 256
#define BB 64
#define DD 1024
#define HH 1024
#define G3 3072

typedef unsigned long long ull;
typedef __attribute__((ext_vector_type(8))) short short8;
typedef __attribute__((ext_vector_type(4))) float f32x4;

__device__ __forceinline__ unsigned short f2bf(float f) {
  union { float f; unsigned int i; } v; v.f = f;
  unsigned int x = v.i;
  return (unsigned short)((x + 0x7fffu + ((x >> 16) & 1u)) >> 16);
}
__device__ __forceinline__ float bf2f(unsigned short u) {
  union { unsigned int i; float f; } v; v.i = ((unsigned int)u) << 16; return v.f;
}
__device__ __forceinline__ f32x4 mfma16(short8 a, short8 b, f32x4 c) {
  return __builtin_amdgcn_mfma_f32_16x16x32_bf16(a, b, c, 0, 0, 0);
}
__device__ __forceinline__ void gload_lds16(const void* g, void* l) {
  __builtin_amdgcn_global_load_lds((const __attribute__((address_space(1))) void*)g,
                                   (__attribute__((address_space(3))) void*)l,
                                   16, 0, 0);
}
// 16B cache-bypass load (coherent from MALL). No tearing risk: reads are
// seq-gated (producer stores proven complete before any read).
__device__ __forceinline__ short8 mall_load16(const unsigned short* p) {
  short8 r;
  asm volatile("global_load_dwordx4 %0, %1, off sc0 sc1" : "=v"(r) : "v"(p));
  return r;
}

// ---------------- f32 -> bf16 convert (vectorized) ----------------
__global__ void k_cvt_bf16(const float* __restrict__ in, unsigned short* __restrict__ out, int n4) {
  int i = blockIdx.x * blockDim.x + threadIdx.x;
  int stride = gridDim.x * blockDim.x;
  for (; i < n4; i += stride) {
    float4 v = ((const float4*)in)[i];
    ushort4 o;
    o.x = f2bf(v.x); o.y = f2bf(v.y); o.z = f2bf(v.z); o.w = f2bf(v.w);
    ((ushort4*)out)[i] = o;
  }
}

// ---------------- context projections + bias fold: E[64][3072] ----------------
__global__ __launch_bounds__(256) void k_ctx(
    const unsigned short* __restrict__ cjb, const unsigned short* __restrict__ heb,
    const unsigned short* __restrict__ Wchb, const unsigned short* __restrict__ Wzhb,
    const float* __restrict__ b_ih, const float* __restrict__ b_hh,
    const float* __restrict__ b_ch, const float* __restrict__ b_zh,
    float* __restrict__ E) {
  __shared__ f32x4 red[4][4][64];   // 16 KB
  int n0 = blockIdx.x * 16;         // 192 blocks
  int tid = threadIdx.x;
  int w = tid >> 6, l = tid & 63, lo = l & 15, hi = l >> 4;
  f32x4 acc[4];
#pragma unroll
  for (int r = 0; r < 4; r++) acc[r] = (f32x4){0.f, 0.f, 0.f, 0.f};
#pragma unroll 4
  for (int kk = 0; kk < 16; kk++) {
    int k = w * 512 + kk * 32;
    const unsigned short* Asrc = (k < 1024) ? cjb : heb;
    const unsigned short* Bsrc = (k < 1024) ? Wchb : Wzhb;
    int kw = (k < 1024) ? k : (k - 1024);
    int kof = kw + hi * 8;
    short8 bf = *(const short8*)(Bsrc + (size_t)(n0 + lo) * 1024 + kof);
#pragma unroll
    for (int r = 0; r < 4; r++) {
      short8 af = *(const short8*)(Asrc + (size_t)(r * 16 + lo) * 1024 + kof);
      acc[r] = mfma16(af, bf, acc[r]);
    }
  }
#pragma unroll
  for (int r = 0; r < 4; r++) red[w][r][l] = acc[r];
  __syncthreads();
  f32x4 s = red[0][w][l];
#pragma unroll
  for (int w2 = 1; w2 < 4; w2++) {
    f32x4 p = red[w2][w][l];
    s[0] += p[0]; s[1] += p[1]; s[2] += p[2]; s[3] += p[3];
  }
  int g = n0 + lo;
  float bias = b_ih[g] + b_ch[g] + b_zh[g] + ((g < 2048) ? b_hh[g] : 0.0f);
#pragma unroll
  for (int j = 0; j < 4; j++) {
    int b = w * 16 + hi * 4 + j;
    E[(size_t)b * G3 + g] = s[j] + bias;
  }
}

// ---------------- gi GEMM + E fold: giE[t*64+b][g] = X@Wih^T + E[b][g] (bf16) --------
__global__ __launch_bounds__(256) void k_gemm_gi(
    const unsigned short* __restrict__ Xb,   // [16384][1024] bf16
    const unsigned short* __restrict__ Wb,   // [3072][1024] bf16
    const float* __restrict__ E,             // [64][3072] f32
    unsigned short* __restrict__ gi) {       // [16384][3072] bf16
  __shared__ unsigned short As[128 * 32];
  __shared__ unsigned short Bs[128 * 32];
  int bid = blockIdx.x;
  int mt = bid & 127;
  int nt = bid >> 7;
  int m0 = mt * 128, n0 = nt * 128;
  int tid = threadIdx.x;
  int w = tid >> 6, l = tid & 63, lo = l & 15, hi = l >> 4;
  int wr = w >> 1, wc = w & 1;
  f32x4 acc[4][4];
#pragma unroll
  for (int i = 0; i < 4; i++)
#pragma unroll
    for (int j = 0; j < 4; j++) acc[i][j] = (f32x4){0.f, 0.f, 0.f, 0.f};
  int srow = tid >> 2;
  int scol = (tid & 3) * 8;
  for (int kt = 0; kt < 32; kt++) {
    int k0 = kt * 32;
    __syncthreads();
    gload_lds16(Xb + (size_t)(m0 + srow) * 1024 + k0 + scol, As + srow * 32 + scol);
    gload_lds16(Xb + (size_t)(m0 + 64 + srow) * 1024 + k0 + scol, As + (64 + srow) * 32 + scol);
    gload_lds16(Wb + (size_t)(n0 + srow) * 1024 + k0 + scol, Bs + srow * 32 + scol);
    gload_lds16(Wb + (size_t)(n0 + 64 + srow) * 1024 + k0 + scol, Bs + (64 + srow) * 32 + scol);
    asm volatile("s_waitcnt vmcnt(0)" ::: "memory");
    __syncthreads();
    short8 a[4], b[4];
#pragma unroll
    for (int i = 0; i < 4; i++) a[i] = *(const short8*)(As + (wr * 64 + i * 16 + lo) * 32 + hi * 8);
#pragma unroll
    for (int i = 0; i < 4; i++) b[i] = *(const short8*)(Bs + (wc * 64 + i * 16 + lo) * 32 + hi * 8);
#pragma unroll
    for (int i = 0; i < 4; i++)
#pragma unroll
      for (int j = 0; j < 4; j++) acc[i][j] = mfma16(a[i], b[j], acc[i][j]);
  }
#pragma unroll
  for (int i = 0; i < 4; i++)
#pragma unroll
    for (int j = 0; j < 4; j++)
#pragma unroll
      for (int e = 0; e < 4; e++) {
        int r = m0 + wr * 64 + i * 16 + hi * 4 + e;
        int c = n0 + wc * 64 + j * 16 + lo;
        float v = acc[i][j][e] + E[(size_t)(r & 63) * G3 + c];
        gi[(size_t)r * G3 + c] = f2bf(v);
      }
}

// ---------------- persistent recurrence kernel (v9: staggered row-groups) -------
// 64 wgs x 256 thr. wg cs owns h cols [cs*16,+16). Rows split into 4 groups of 16.
// Phases p = 0..1023: group g=p&3, step t=p>>2 (stagger: (0,t),(1,t),(2,t),(3,t)).
// Wave kq: K-slice [kq*256,+256) for every group's GEMM; epilogue owner of group kq.
// Per phase: [vmcnt-wait pre-issued h frags] -> 24 MFMA -> red write ->
//   poll(phase p+1) + EARLY-ISSUE its h loads (+gi prefetch if next is own group)
//   -> lgkmcnt(0) + raw s_barrier (h loads stay in flight!) ->
//   wave g: reduce, gates, publish h(t+1), drain, seq, out stores.
// Latency of publish->poll->load chain hides under 3 other groups' phases.
// hbuf[g][slot=t&1][blk=cs][16 rows][16 cols] bf16; seq[cs][g] (64B-spaced);
// h_prev[0] feed: LDS h0f[4 slots][16] (row 0 in group 0, wave 0 of each wg).
__global__ __launch_bounds__(256) void k_rnn(
    const unsigned short* __restrict__ giE,   // [256*64][3072] bf16 (incl E)
    const unsigned short* __restrict__ Whhb,  // [3072][1024] bf16
    const float* __restrict__ b_hh,
    const float* __restrict__ h0,
    const int* __restrict__ length,
    unsigned short* __restrict__ hbuf,        // [4][2][64][256] ushort
    float* __restrict__ out,                  // [256][64][1024] f32
    float* __restrict__ hn,                   // [64][1024] f32
    unsigned int* __restrict__ seq) {         // [64 cs][4 g] words, 64B-spaced
  extern __shared__ char smem[];
  unsigned short* wlds = (unsigned short*)smem;          // 96 KB [96 frag][64 lane][8]
  f32x4* red = (f32x4*)(smem + 98304);                   // 24 KB [2 par][4 q][3 s][64 l]
  float* h0f = (float*)(smem + 98304 + 24576);           // [4 slot][16]

  const int cs = blockIdx.x, j0 = cs * 16;
  const int tid = threadIdx.x;
  const int kq = tid >> 6, l = tid & 63, lo = l & 15, hi = l >> 4;
  const int col = j0 + lo;

  // ---- weight preload: wave kq's 24 frags in fragment order ----
#pragma unroll
  for (int kk = 0; kk < 8; ++kk)
#pragma unroll
    for (int s = 0; s < 3; ++s) {
      int f = (kq * 8 + kk) * 3 + s;
      short8 v = *(const short8*)(Whhb + (size_t)(s * 1024 + j0 + lo) * 1024 + kq * 256 + kk * 32 + hi * 8);
      ((short8*)wlds)[f * 64 + l] = v;
    }

  const float bhhn = b_hh[2048 + col];
  float hown[4];
  int len4[4];
#pragma unroll
  for (int j = 0; j < 4; ++j) {
    int b = kq * 16 + hi * 4 + j;
    hown[j] = h0[(size_t)b * 1024 + col];
    len4[j] = length[b];
  }
  // ---- publish h(0) for own group into slot 0 ----
  {
    unsigned short* dst = hbuf + ((size_t)(kq * 2 + 0) * 64 + cs) * 256;
#pragma unroll
    for (int j = 0; j < 4; ++j) {
      unsigned int mine = f2bf(hown[j]);
      unsigned int oth = __shfl_xor(mine, 1, 64);
      if (!(lo & 1))
        __hip_atomic_store((unsigned int*)(dst + (hi * 4 + j) * 16 + lo),
                           mine | (oth << 16), __ATOMIC_RELAXED, __HIP_MEMORY_SCOPE_AGENT);
    }
  }
  if (kq == 0 && hi == 0) h0f[0 * 16 + lo] = hown[0];
  // ---- gi prefetch for (kq, t=0) ----
  unsigned short girP[12];
#pragma unroll
  for (int s = 0; s < 3; ++s)
#pragma unroll
    for (int j = 0; j < 4; ++j)
      girP[s * 4 + j] = giE[(size_t)(kq * 16 + hi * 4 + j) * G3 + s * 1024 + col];
  __syncthreads();
  asm volatile("s_waitcnt vmcnt(0)" ::: "memory");   // drain h(0) stores
  if (l == 0)
    __hip_atomic_store(&seq[(cs * 4 + kq) * 16], 1u, __ATOMIC_RELAXED, __HIP_MEMORY_SCOPE_AGENT);

  short8 aE[8], aO[8];

#define POLL_ISSUE(GNX, TNX, AN)                                                        \
  {                                                                                     \
    const unsigned int* sp = seq + ((size_t)(kq * 16 + (l & 15)) * 4 + (GNX)) * 16;     \
    unsigned int tgt = (unsigned int)((TNX) + 1);                                       \
    for (;;) {                                                                          \
      unsigned int v = __hip_atomic_load(sp, __ATOMIC_RELAXED, __HIP_MEMORY_SCOPE_AGENT);\
      if (__all(v >= tgt)) break;                                                       \
      __builtin_amdgcn_s_sleep(1);                                                      \
    }                                                                                   \
    const unsigned short* base = hbuf + ((size_t)((GNX) * 2 + ((TNX) & 1)) * 64) * 256; \
    _Pragma("unroll")                                                                   \
    for (int kk = 0; kk < 8; ++kk) {                                                    \
      int blk = kq * 16 + kk * 2 + (hi >> 1);                                           \
      AN[kk] = mall_load16(base + (size_t)blk * 256 + lo * 16 + (hi & 1) * 8);          \
    }                                                                                   \
    if ((GNX) == kq && (TNX) < TT) {                                                    \
      const unsigned short* gb = giE + (size_t)(TNX) * 64 * G3;                         \
      _Pragma("unroll")                                                                 \
      for (int s = 0; s < 3; ++s)                                                       \
        _Pragma("unroll")                                                               \
        for (int j = 0; j < 4; ++j)                                                     \
          girP[s * 4 + j] = gb[(size_t)(kq * 16 + hi * 4 + j) * G3 + s * 1024 + col];   \
    }                                                                                   \
  }

#define PHASE(P, AC, AN)                                                                \
  {                                                                                     \
    const int g = (P) & 3;                                                              \
    const int t = (P) >> 2;                                                             \
    const int par = (P) & 1;                                                            \
    asm volatile("s_waitcnt vmcnt(0)" ::: "memory");                                    \
    __builtin_amdgcn_sched_barrier(0);                                                  \
    f32x4 ac0 = {0.f, 0.f, 0.f, 0.f}, ac1 = ac0, ac2 = ac0;                             \
    _Pragma("unroll")                                                                   \
    for (int kk = 0; kk < 8; ++kk) {                                                    \
      const short8* wf = ((const short8*)wlds) + (size_t)((kq * 8 + kk) * 3) * 64 + l;  \
      short8 b0 = wf[0];                                                                \
      short8 b1 = wf[64];                                                               \
      short8 b2 = wf[128];                                                              \
      ac0 = mfma16(AC[kk], b0, ac0);                                                    \
      ac1 = mfma16(AC[kk], b1, ac1);                                                    \
      ac2 = mfma16(AC[kk], b2, ac2);                                                    \
    }                                                                                   \
    red[((size_t)(par * 4 + kq) * 3 + 0) * 64 + l] = ac0;                               \
    red[((size_t)(par * 4 + kq) * 3 + 1) * 64 + l] = ac1;                               \
    red[((size_t)(par * 4 + kq) * 3 + 2) * 64 + l] = ac2;                               \
    if ((P) + 1 < 4 * TT) {                                                             \
      const int gnx = ((P) + 1) & 3, tnx = ((P) + 1) >> 2;                              \
      POLL_ISSUE(gnx, tnx, AN);                                                         \
    }                                                                                   \
    asm volatile("s_waitcnt lgkmcnt(0)" ::: "memory");                                  \
    __builtin_amdgcn_s_barrier();                                                       \
    __builtin_amdgcn_sched_barrier(0);                                                  \
    if (kq == g) {                                                                      \
      f32x4 fin[3];                                                                     \
      _Pragma("unroll")                                                                 \
      for (int s = 0; s < 3; ++s) {                                                     \
        f32x4 v = red[((size_t)(par * 4 + 0) * 3 + s) * 64 + l];                        \
        _Pragma("unroll")                                                               \
        for (int q = 1; q < 4; ++q) {                                                   \
          f32x4 pp = red[((size_t)(par * 4 + q) * 3 + s) * 64 + l];                     \
          v[0] += pp[0]; v[1] += pp[1]; v[2] += pp[2]; v[3] += pp[3];                   \
        }                                                                               \
        fin[s] = v;                                                                     \
      }                                                                                 \
      float h0p = (g == 0) ? __shfl(hown[0], lo, 64) : h0f[(t & 3) * 16 + lo];          \
      float hv[4];                                                                      \
      _Pragma("unroll")                                                                 \
      for (int j = 0; j < 4; ++j) {                                                     \
        float R = fin[0][j] + bf2f(girP[0 * 4 + j]);                                    \
        float I = fin[1][j] + bf2f(girP[1 * 4 + j]);                                    \
        float rg = 1.f / (1.f + __expf(-R));                                            \
        float ig = 1.f / (1.f + __expf(-I));                                            \
        float nx = bf2f(girP[2 * 4 + j]) + rg * (fin[2][j] + bhhn);                     \
        nx = fminf(15.f, fmaxf(-15.f, nx));                                             \
        float e2 = __expf(2.f * nx);                                                    \
        float ng = (e2 - 1.f) / (e2 + 1.f);                                             \
        float hy = ng + ig * (hown[j] - ng);                                            \
        float res = (t < len4[j]) ? hy : h0p;                                           \
        hv[j] = res;                                                                    \
        hown[j] = res;                                                                  \
      }                                                                                 \
      if (t < TT - 1) {                                                                 \
        unsigned short* dst = hbuf + ((size_t)(g * 2 + ((t + 1) & 1)) * 64 + cs) * 256; \
        _Pragma("unroll")                                                               \
        for (int j = 0; j < 4; ++j) {                                                   \
          unsigned int mine = f2bf(hv[j]);                                              \
          unsigned int oth = __shfl_xor(mine, 1, 64);                                   \
          if (!(lo & 1))                                                                \
            __hip_atomic_store((unsigned int*)(dst + (hi * 4 + j) * 16 + lo),           \
                               mine | (oth << 16), __ATOMIC_RELAXED,                    \
                               __HIP_MEMORY_SCOPE_AGENT);                               \
        }                                                                               \
        if (g == 0 && hi == 0) h0f[((t + 1) & 3) * 16 + lo] = hv[0];                    \
        asm volatile("s_waitcnt vmcnt(0)" ::: "memory");                                \
        if (l == 0)                                                                     \
          __hip_atomic_store(&seq[(cs * 4 + g) * 16], (unsigned int)(t + 2),            \
                             __ATOMIC_RELAXED, __HIP_MEMORY_SCOPE_AGENT);               \
        _Pragma("unroll")                                                               \
        for (int j = 0; j < 4; ++j) {                                                   \
          int b = g * 16 + hi * 4 + j;                                                  \
          out[(size_t)t * (BB * HH) + (size_t)b * 1024 + col] = hv[j];                  \
        }                                                                               \
      } else {                                                                          \
        _Pragma("unroll")                                                               \
        for (int j = 0; j < 4; ++j) {                                                   \
          int b = g * 16 + hi * 4 + j;                                                  \
          out[(size_t)t * (BB * HH) + (size_t)b * 1024 + col] = hv[j];                  \
          hn[(size_t)b * 1024 + col] = hv[j];                                           \
        }                                                                               \
      }                                                                                 \
    }                                                                                   \
  }

  // pre-loop: poll (g=0,t=0) + issue into aE
  POLL_ISSUE(0, 0, aE);

  for (int p2 = 0; p2 < 2 * TT; ++p2) {
    int p = p2 * 2;
    PHASE(p, aE, aO);
    PHASE(p + 1, aO, aE);
  }
#undef PHASE
#undef POLL_ISSUE
}

// ---------------- host ----------------
extern "C" void kernel_launch(void* const* d_in, const int* in_sizes, int n_in,
                              void* d_out, int out_size, void* d_ws, size_t ws_size,
                              hipStream_t stream) {
  const float* input_ = (const float*)d_in[0];
  const int* length   = (const int*)d_in[1];
  const float* h0     = (const float*)d_in[2];
  const float* cj     = (const float*)d_in[3];
  const float* he     = (const float*)d_in[4];
  const float* w_ih   = (const float*)d_in[5];
  const float* w_hh   = (const float*)d_in[6];
  const float* w_ch   = (const float*)d_in[7];
  const float* w_zh   = (const float*)d_in[8];
  const float* b_ih   = (const float*)d_in[9];
  const float* b_hh   = (const float*)d_in[10];
  const float* b_ch   = (const float*)d_in[11];
  const float* b_zh   = (const float*)d_in[12];

  char* ws = (char*)d_ws;
  const size_t OFF_SEQ   = 0;               // 16 KB: [64][4] words, 64B-spaced
  const size_t OFF_HBUF  = 16384;           // 256 KB: [4][2][64][512B]
  const size_t OFF_XB    = 524288;
  const size_t OFF_WIHB  = OFF_XB + 33554432ull;
  const size_t OFF_WHHB  = OFF_WIHB + 6291456ull;
  const size_t OFF_WCHB  = OFF_WHHB + 6291456ull;
  const size_t OFF_WZHB  = OFF_WCHB + 6291456ull;
  const size_t OFF_CJB   = OFF_WZHB + 6291456ull;
  const size_t OFF_HEB   = OFF_CJB + 131072ull;
  const size_t OFF_E     = OFF_HEB + 131072ull;
  const size_t OFF_GI    = OFF_E + 786432ull;

  unsigned int* seq     = (unsigned int*)(ws + OFF_SEQ);
  unsigned short* hbuf  = (unsigned short*)(ws + OFF_HBUF);
  unsigned short* Xb    = (unsigned short*)(ws + OFF_XB);
  unsigned short* Wihb  = (unsigned short*)(ws + OFF_WIHB);
  unsigned short* Whhb  = (unsigned short*)(ws + OFF_WHHB);
  unsigned short* Wchb  = (unsigned short*)(ws + OFF_WCHB);
  unsigned short* Wzhb  = (unsigned short*)(ws + OFF_WZHB);
  unsigned short* cjb   = (unsigned short*)(ws + OFF_CJB);
  unsigned short* heb   = (unsigned short*)(ws + OFF_HEB);
  float* E              = (float*)(ws + OFF_E);
  unsigned short* gi    = (unsigned short*)(ws + OFF_GI);

  float* out = (float*)d_out;
  float* hn  = out + 16777216;   // T*B*H

  hipFuncSetAttribute((const void*)k_rnn, hipFuncAttributeMaxDynamicSharedMemorySize, 123136);

  hipMemsetAsync(seq, 0, 16384, stream);
  k_cvt_bf16<<<2048, 256, 0, stream>>>(input_, Xb, 16777216 / 4);
  k_cvt_bf16<<<1024, 256, 0, stream>>>(w_ih, Wihb, 3145728 / 4);
  k_cvt_bf16<<<1024, 256, 0, stream>>>(w_hh, Whhb, 3145728 / 4);
  k_cvt_bf16<<<1024, 256, 0, stream>>>(w_ch, Wchb, 3145728 / 4);
  k_cvt_bf16<<<1024, 256, 0, stream>>>(w_zh, Wzhb, 3145728 / 4);
  k_cvt_bf16<<<64, 256, 0, stream>>>(cj, cjb, 65536 / 4);
  k_cvt_bf16<<<64, 256, 0, stream>>>(he, heb, 65536 / 4);
  k_ctx<<<192, 256, 0, stream>>>(cjb, heb, Wchb, Wzhb, b_ih, b_hh, b_ch, b_zh, E);
  k_gemm_gi<<<3072, 256, 0, stream>>>(Xb, Wihb, E, gi);
  k_rnn<<<64, 256, 123136, stream>>>(gi, Whhb, b_hh, h0, length, hbuf, out, hn, seq);
}

// Round 11
// 1407.080 us; speedup vs baseline: 2.0549x; 2.0549x over previous
//
#include <hip/hip_runtime.h>
#include <stdint.h>

#define TT 256
#define BB 64
#define DD 1024
#define HH 1024
#define G3 3072

typedef unsigned long long ull;
typedef __attribute__((ext_vector_type(8))) short short8;
typedef __attribute__((ext_vector_type(4))) float f32x4;

__device__ __forceinline__ unsigned short f2bf(float f) {
  union { float f; unsigned int i; } v; v.f = f;
  unsigned int x = v.i;
  return (unsigned short)((x + 0x7fffu + ((x >> 16) & 1u)) >> 16);
}
__device__ __forceinline__ float bf2f(unsigned short u) {
  union { unsigned int i; float f; } v; v.i = ((unsigned int)u) << 16; return v.f;
}
__device__ __forceinline__ f32x4 mfma16(short8 a, short8 b, f32x4 c) {
  return __builtin_amdgcn_mfma_f32_16x16x32_bf16(a, b, c, 0, 0, 0);
}
__device__ __forceinline__ void gload_lds16(const void* g, void* l) {
  __builtin_amdgcn_global_load_lds((const __attribute__((address_space(1))) void*)g,
                                   (__attribute__((address_space(3))) void*)l,
                                   16, 0, 0);
}
// 16B cache-bypass load (coherent from MALL). Reads are seq-gated.
// NOTE: raw asm load => compiler does NOT insert s_waitcnt; callers MUST
// wait with explicit counted vmcnt before consuming the result (rule #18).
__device__ __forceinline__ short8 mall_load16(const unsigned short* p) {
  short8 r;
  asm volatile("global_load_dwordx4 %0, %1, off sc0 sc1" : "=v"(r) : "v"(p));
  return r;
}

// ---------------- f32 -> bf16 convert (vectorized) ----------------
__global__ void k_cvt_bf16(const float* __restrict__ in, unsigned short* __restrict__ out, int n4) {
  int i = blockIdx.x * blockDim.x + threadIdx.x;
  int stride = gridDim.x * blockDim.x;
  for (; i < n4; i += stride) {
    float4 v = ((const float4*)in)[i];
    ushort4 o;
    o.x = f2bf(v.x); o.y = f2bf(v.y); o.z = f2bf(v.z); o.w = f2bf(v.w);
    ((ushort4*)out)[i] = o;
  }
}

// ---------------- context projections + bias fold: E[64][3072] ----------------
__global__ __launch_bounds__(256) void k_ctx(
    const unsigned short* __restrict__ cjb, const unsigned short* __restrict__ heb,
    const unsigned short* __restrict__ Wchb, const unsigned short* __restrict__ Wzhb,
    const float* __restrict__ b_ih, const float* __restrict__ b_hh,
    const float* __restrict__ b_ch, const float* __restrict__ b_zh,
    float* __restrict__ E) {
  __shared__ f32x4 red[4][4][64];   // 16 KB
  int n0 = blockIdx.x * 16;         // 192 blocks
  int tid = threadIdx.x;
  int w = tid >> 6, l = tid & 63, lo = l & 15, hi = l >> 4;
  f32x4 acc[4];
#pragma unroll
  for (int r = 0; r < 4; r++) acc[r] = (f32x4){0.f, 0.f, 0.f, 0.f};
#pragma unroll 4
  for (int kk = 0; kk < 16; kk++) {
    int k = w * 512 + kk * 32;
    const unsigned short* Asrc = (k < 1024) ? cjb : heb;
    const unsigned short* Bsrc = (k < 1024) ? Wchb : Wzhb;
    int kw = (k < 1024) ? k : (k - 1024);
    int kof = kw + hi * 8;
    short8 bf = *(const short8*)(Bsrc + (size_t)(n0 + lo) * 1024 + kof);
#pragma unroll
    for (int r = 0; r < 4; r++) {
      short8 af = *(const short8*)(Asrc + (size_t)(r * 16 + lo) * 1024 + kof);
      acc[r] = mfma16(af, bf, acc[r]);
    }
  }
#pragma unroll
  for (int r = 0; r < 4; r++) red[w][r][l] = acc[r];
  __syncthreads();
  f32x4 s = red[0][w][l];
#pragma unroll
  for (int w2 = 1; w2 < 4; w2++) {
    f32x4 p = red[w2][w][l];
    s[0] += p[0]; s[1] += p[1]; s[2] += p[2]; s[3] += p[3];
  }
  int g = n0 + lo;
  float bias = b_ih[g] + b_ch[g] + b_zh[g] + ((g < 2048) ? b_hh[g] : 0.0f);
#pragma unroll
  for (int j = 0; j < 4; j++) {
    int b = w * 16 + hi * 4 + j;
    E[(size_t)b * G3 + g] = s[j] + bias;
  }
}

// ---------------- gi GEMM + E fold: giE[t*64+b][g] = X@Wih^T + E[b][g] (bf16) --------
__global__ __launch_bounds__(256) void k_gemm_gi(
    const unsigned short* __restrict__ Xb,   // [16384][1024] bf16
    const unsigned short* __restrict__ Wb,   // [3072][1024] bf16
    const float* __restrict__ E,             // [64][3072] f32
    unsigned short* __restrict__ gi) {       // [16384][3072] bf16
  __shared__ unsigned short As[128 * 32];
  __shared__ unsigned short Bs[128 * 32];
  int bid = blockIdx.x;
  int mt = bid & 127;
  int nt = bid >> 7;
  int m0 = mt * 128, n0 = nt * 128;
  int tid = threadIdx.x;
  int w = tid >> 6, l = tid & 63, lo = l & 15, hi = l >> 4;
  int wr = w >> 1, wc = w & 1;
  f32x4 acc[4][4];
#pragma unroll
  for (int i = 0; i < 4; i++)
#pragma unroll
    for (int j = 0; j < 4; j++) acc[i][j] = (f32x4){0.f, 0.f, 0.f, 0.f};
  int srow = tid >> 2;
  int scol = (tid & 3) * 8;
  for (int kt = 0; kt < 32; kt++) {
    int k0 = kt * 32;
    __syncthreads();
    gload_lds16(Xb + (size_t)(m0 + srow) * 1024 + k0 + scol, As + srow * 32 + scol);
    gload_lds16(Xb + (size_t)(m0 + 64 + srow) * 1024 + k0 + scol, As + (64 + srow) * 32 + scol);
    gload_lds16(Wb + (size_t)(n0 + srow) * 1024 + k0 + scol, Bs + srow * 32 + scol);
    gload_lds16(Wb + (size_t)(n0 + 64 + srow) * 1024 + k0 + scol, Bs + (64 + srow) * 32 + scol);
    asm volatile("s_waitcnt vmcnt(0)" ::: "memory");
    __syncthreads();
    short8 a[4], b[4];
#pragma unroll
    for (int i = 0; i < 4; i++) a[i] = *(const short8*)(As + (wr * 64 + i * 16 + lo) * 32 + hi * 8);
#pragma unroll
    for (int i = 0; i < 4; i++) b[i] = *(const short8*)(Bs + (wc * 64 + i * 16 + lo) * 32 + hi * 8);
#pragma unroll
    for (int i = 0; i < 4; i++)
#pragma unroll
      for (int j = 0; j < 4; j++) acc[i][j] = mfma16(a[i], b[j], acc[i][j]);
  }
#pragma unroll
  for (int i = 0; i < 4; i++)
#pragma unroll
    for (int j = 0; j < 4; j++)
#pragma unroll
      for (int e = 0; e < 4; e++) {
        int r = m0 + wr * 64 + i * 16 + hi * 4 + e;
        int c = n0 + wc * 64 + j * 16 + lo;
        float v = acc[i][j][e] + E[(size_t)(r & 63) * G3 + c];
        gi[(size_t)r * G3 + c] = f2bf(v);
      }
}

// ---------------- persistent recurrence kernel (v11: v10 + correct waits) ------
// 64 wgs x 128 thr (2 waves). wg cs owns h cols [cs*16,+16). Wave w owns rows
// [w*32,+32) x 16 cols x FULL K=1024 -> no cross-wave reduce, NO barriers in the
// 256-step loop. Whh in LDS (96 KB), B-frags reused across both row-tiles.
// A loads double-buffered (16-frag chunks) with COUNTED vmcnt waits +
// sched_barrier(0) fences (rule #18 — raw-asm loads get no compiler waitcnt).
// Poll's compiler-inserted vmcnt(0) drains stragglers -> counts are exact.
__global__ __launch_bounds__(128) void k_rnn(
    const unsigned short* __restrict__ giE,   // [256*64][3072] bf16 (incl E)
    const unsigned short* __restrict__ Whhb,  // [3072][1024] bf16
    const float* __restrict__ b_hh,
    const float* __restrict__ h0,
    const int* __restrict__ length,
    unsigned short* __restrict__ hbuf,        // [2][64][64][16] ushort
    float* __restrict__ out,                  // [256][64][1024] f32
    float* __restrict__ hn,                   // [64][1024] f32
    unsigned int* __restrict__ seq) {         // [128] words, 64B-spaced
  extern __shared__ char smem[];
  unsigned short* wlds = (unsigned short*)smem;   // 96 KB [96 frag=kk*3+s][64 lane][8]
  float* h0f = (float*)(smem + 98304);            // [2][16]

  const int cs = blockIdx.x, j0 = cs * 16;
  const int tid = threadIdx.x;
  const int w = tid >> 6, l = tid & 63, lo = l & 15, hi = l >> 4;
  const int rowbase = w * 32;
  const int col = j0 + lo;

  // ---- weight preload: wave w loads kk in [w*16, w*16+16) ----
#pragma unroll
  for (int k2 = 0; k2 < 16; ++k2) {
    int kk = w * 16 + k2;
#pragma unroll
    for (int s = 0; s < 3; ++s) {
      int f = kk * 3 + s;
      short8 v = *(const short8*)(Whhb + (size_t)(s * 1024 + j0 + lo) * 1024 + kk * 32 + hi * 8);
      ((short8*)wlds)[f * 64 + l] = v;
    }
  }
  const float bhhn = b_hh[2048 + col];
  float hA[4], hB[4];
  int lenA[4], lenB[4];
#pragma unroll
  for (int j = 0; j < 4; ++j) {
    int rA = rowbase + hi * 4 + j, rB = rA + 16;
    hA[j] = h0[(size_t)rA * 1024 + col]; lenA[j] = length[rA];
    hB[j] = h0[(size_t)rB * 1024 + col]; lenB[j] = length[rB];
  }
  // ---- publish h(0) into slot 0 ----
  {
    unsigned short* dst = hbuf + (size_t)cs * 1024;
#pragma unroll
    for (int j = 0; j < 4; ++j) {
      unsigned int mA = f2bf(hA[j]), mB = f2bf(hB[j]);
      unsigned int oA = __shfl_xor(mA, 1, 64), oB = __shfl_xor(mB, 1, 64);
      if (!(lo & 1)) {
        int rr = rowbase + hi * 4 + j;
        __hip_atomic_store((unsigned int*)(dst + rr * 16 + lo), mA | (oA << 16),
                           __ATOMIC_RELAXED, __HIP_MEMORY_SCOPE_AGENT);
        __hip_atomic_store((unsigned int*)(dst + (rr + 16) * 16 + lo), mB | (oB << 16),
                           __ATOMIC_RELAXED, __HIP_MEMORY_SCOPE_AGENT);
      }
    }
  }
  if (w == 0 && hi == 0) h0f[lo] = hA[0];   // exact f32 h(0)[0][col]
  __syncthreads();   // init only: wlds + h0f ready
  asm volatile("s_waitcnt vmcnt(0)" ::: "memory");
  if (l == 0)
    __hip_atomic_store(&seq[(cs * 2 + w) * 16], 1u, __ATOMIC_RELAXED, __HIP_MEMORY_SCOPE_AGENT);
  // ---- gir prefetch for t=0: 24 ushort (2 rt x 3 s x 4 j) ----
  unsigned short gir[24];
#pragma unroll
  for (int r2 = 0; r2 < 2; ++r2)
#pragma unroll
    for (int s = 0; s < 3; ++s)
#pragma unroll
      for (int j = 0; j < 4; ++j)
        gir[(r2 * 3 + s) * 4 + j] =
            giE[(size_t)(rowbase + r2 * 16 + hi * 4 + j) * G3 + s * 1024 + col];

#define ISSUE(c, X)                                                                    \
  _Pragma("unroll") for (int k2 = 0; k2 < 8; ++k2) {                                   \
    int kk = (c) * 8 + k2;                                                             \
    size_t cb = (size_t)(kk * 2 + (hi >> 1));                                          \
    X[k2 * 2 + 0] = mall_load16(base + (cb * 64 + rowbase + lo) * 16 + (hi & 1) * 8);  \
    X[k2 * 2 + 1] = mall_load16(base + (cb * 64 + rowbase + 16 + lo) * 16 + (hi & 1) * 8); \
  }
#define WAITV(N)                                                                       \
  asm volatile("s_waitcnt vmcnt(" #N ")" ::: "memory");                                \
  __builtin_amdgcn_sched_barrier(0)
#define CRUNCH(c, X)                                                                   \
  _Pragma("unroll") for (int k2 = 0; k2 < 8; ++k2) {                                   \
    int kk = (c) * 8 + k2;                                                             \
    const short8* wf = ((const short8*)wlds) + (size_t)(kk * 3) * 64 + l;              \
    short8 b0 = wf[0], b1 = wf[64], b2 = wf[128];                                      \
    a00 = mfma16(X[k2 * 2 + 0], b0, a00);                                              \
    a01 = mfma16(X[k2 * 2 + 0], b1, a01);                                              \
    a02 = mfma16(X[k2 * 2 + 0], b2, a02);                                              \
    a10 = mfma16(X[k2 * 2 + 1], b0, a10);                                              \
    a11 = mfma16(X[k2 * 2 + 1], b1, a11);                                              \
    a12 = mfma16(X[k2 * 2 + 1], b2, a12);                                              \
  }

  for (int t = 0; t < TT; ++t) {
    // ---- poll all 128 producer words (2 per lane); compiler's vmcnt(0) before
    // the compare drains all prior vmem -> vmcnt baseline 0 after this ----
    {
      const unsigned int* sp0 = seq + (size_t)(2 * l) * 16;
      const unsigned int* sp1 = sp0 + 16;
      unsigned int tgt = (unsigned int)(t + 1);
      for (;;) {
        unsigned int v0 = __hip_atomic_load(sp0, __ATOMIC_RELAXED, __HIP_MEMORY_SCOPE_AGENT);
        unsigned int v1 = __hip_atomic_load(sp1, __ATOMIC_RELAXED, __HIP_MEMORY_SCOPE_AGENT);
        if (__all((v0 >= tgt) && (v1 >= tgt))) break;
        __builtin_amdgcn_s_sleep(1);
      }
    }
    // ---- chunked A loads + MFMA (full K for 2 row-tiles), counted waits ----
    const unsigned short* base = hbuf + ((size_t)(t & 1) * 64) * 1024;
    f32x4 a00 = {0.f, 0.f, 0.f, 0.f}, a01 = a00, a02 = a00, a10 = a00, a11 = a00, a12 = a00;
    {
      short8 XA[16], XB[16];
      ISSUE(0, XA);        // 16 outstanding
      ISSUE(1, XB);        // 32 outstanding
      WAITV(16);           // chunk 0 landed
      CRUNCH(0, XA);
      ISSUE(2, XA);        // <=32 outstanding
      WAITV(16);           // chunk 1 landed
      CRUNCH(1, XB);
      ISSUE(3, XB);        // <=32 outstanding
      WAITV(16);           // chunk 2 landed
      CRUNCH(2, XA);
      WAITV(0);            // chunk 3 landed
      CRUNCH(3, XB);
    }
    // ---- gates for 8 rows/lane ----
    float h0p = (w == 0) ? __shfl(hA[0], lo, 64) : h0f[(t & 1) * 16 + lo];
    float rA[4], rB[4];
#pragma unroll
    for (int j = 0; j < 4; ++j) {
      float R = a00[j] + bf2f(gir[0 * 4 + j]);
      float I = a01[j] + bf2f(gir[1 * 4 + j]);
      float rg = 1.f / (1.f + __expf(-R));
      float ig = 1.f / (1.f + __expf(-I));
      float nx = bf2f(gir[2 * 4 + j]) + rg * (a02[j] + bhhn);
      nx = fminf(15.f, fmaxf(-15.f, nx));
      float e2 = __expf(2.f * nx);
      float ng = (e2 - 1.f) / (e2 + 1.f);
      float hy = ng + ig * (hA[j] - ng);
      rA[j] = (t < lenA[j]) ? hy : h0p;
    }
#pragma unroll
    for (int j = 0; j < 4; ++j) {
      float R = a10[j] + bf2f(gir[(3 + 0) * 4 + j]);
      float I = a11[j] + bf2f(gir[(3 + 1) * 4 + j]);
      float rg = 1.f / (1.f + __expf(-R));
      float ig = 1.f / (1.f + __expf(-I));
      float nx = bf2f(gir[(3 + 2) * 4 + j]) + rg * (a12[j] + bhhn);
      nx = fminf(15.f, fmaxf(-15.f, nx));
      float e2 = __expf(2.f * nx);
      float ng = (e2 - 1.f) / (e2 + 1.f);
      float hy = ng + ig * (hB[j] - ng);
      rB[j] = (t < lenB[j]) ? hy : h0p;
    }
#pragma unroll
    for (int j = 0; j < 4; ++j) { hA[j] = rA[j]; hB[j] = rB[j]; }
    if (t < TT - 1) {
      // ---- publish h(t+1) + h0f + signal ----
      unsigned short* dst = hbuf + ((size_t)((t + 1) & 1) * 64 + cs) * 1024;
#pragma unroll
      for (int j = 0; j < 4; ++j) {
        unsigned int mA = f2bf(hA[j]), mB = f2bf(hB[j]);
        unsigned int oA = __shfl_xor(mA, 1, 64), oB = __shfl_xor(mB, 1, 64);
        if (!(lo & 1)) {
          int rr = rowbase + hi * 4 + j;
          __hip_atomic_store((unsigned int*)(dst + rr * 16 + lo), mA | (oA << 16),
                             __ATOMIC_RELAXED, __HIP_MEMORY_SCOPE_AGENT);
          __hip_atomic_store((unsigned int*)(dst + (rr + 16) * 16 + lo), mB | (oB << 16),
                             __ATOMIC_RELAXED, __HIP_MEMORY_SCOPE_AGENT);
        }
      }
      if (w == 0 && hi == 0) h0f[((t + 1) & 1) * 16 + lo] = hA[0];
      asm volatile("s_waitcnt vmcnt(0) lgkmcnt(0)" ::: "memory");
      if (l == 0)
        __hip_atomic_store(&seq[(cs * 2 + w) * 16], (unsigned int)(t + 2),
                           __ATOMIC_RELAXED, __HIP_MEMORY_SCOPE_AGENT);
      // ---- off critical path: out(t) stores + gir(t+1) prefetch ----
#pragma unroll
      for (int j = 0; j < 4; ++j) {
        int rr = rowbase + hi * 4 + j;
        out[(size_t)t * (BB * HH) + (size_t)rr * 1024 + col] = rA[j];
        out[(size_t)t * (BB * HH) + (size_t)(rr + 16) * 1024 + col] = rB[j];
      }
      const unsigned short* gb = giE + (size_t)(t + 1) * 64 * G3;
#pragma unroll
      for (int r2 = 0; r2 < 2; ++r2)
#pragma unroll
        for (int s = 0; s < 3; ++s)
#pragma unroll
          for (int j = 0; j < 4; ++j)
            gir[(r2 * 3 + s) * 4 + j] =
                gb[(size_t)(rowbase + r2 * 16 + hi * 4 + j) * G3 + s * 1024 + col];
    } else {
      // ---- tail: out(255) + hn ----
#pragma unroll
      for (int j = 0; j < 4; ++j) {
        int rr = rowbase + hi * 4 + j;
        out[(size_t)t * (BB * HH) + (size_t)rr * 1024 + col] = rA[j];
        out[(size_t)t * (BB * HH) + (size_t)(rr + 16) * 1024 + col] = rB[j];
        hn[(size_t)rr * 1024 + col] = rA[j];
        hn[(size_t)(rr + 16) * 1024 + col] = rB[j];
      }
    }
  }
#undef ISSUE
#undef WAITV
#undef CRUNCH
}

// ---------------- host ----------------
extern "C" void kernel_launch(void* const* d_in, const int* in_sizes, int n_in,
                              void* d_out, int out_size, void* d_ws, size_t ws_size,
                              hipStream_t stream) {
  const float* input_ = (const float*)d_in[0];
  const int* length   = (const int*)d_in[1];
  const float* h0     = (const float*)d_in[2];
  const float* cj     = (const float*)d_in[3];
  const float* he     = (const float*)d_in[4];
  const float* w_ih   = (const float*)d_in[5];
  const float* w_hh   = (const float*)d_in[6];
  const float* w_ch   = (const float*)d_in[7];
  const float* w_zh   = (const float*)d_in[8];
  const float* b_ih   = (const float*)d_in[9];
  const float* b_hh   = (const float*)d_in[10];
  const float* b_ch   = (const float*)d_in[11];
  const float* b_zh   = (const float*)d_in[12];

  char* ws = (char*)d_ws;
  const size_t OFF_SEQ   = 0;               // 16 KB: 128 words, 64B-spaced
  const size_t OFF_HBUF  = 16384;           // 256 KB: [2][64][64][16] ushort
  const size_t OFF_XB    = 524288;
  const size_t OFF_WIHB  = OFF_XB + 33554432ull;
  const size_t OFF_WHHB  = OFF_WIHB + 6291456ull;
  const size_t OFF_WCHB  = OFF_WHHB + 6291456ull;
  const size_t OFF_WZHB  = OFF_WCHB + 6291456ull;
  const size_t OFF_CJB   = OFF_WZHB + 6291456ull;
  const size_t OFF_HEB   = OFF_CJB + 131072ull;
  const size_t OFF_E     = OFF_HEB + 131072ull;
  const size_t OFF_GI    = OFF_E + 786432ull;

  unsigned int* seq     = (unsigned int*)(ws + OFF_SEQ);
  unsigned short* hbuf  = (unsigned short*)(ws + OFF_HBUF);
  unsigned short* Xb    = (unsigned short*)(ws + OFF_XB);
  unsigned short* Wihb  = (unsigned short*)(ws + OFF_WIHB);
  unsigned short* Whhb  = (unsigned short*)(ws + OFF_WHHB);
  unsigned short* Wchb  = (unsigned short*)(ws + OFF_WCHB);
  unsigned short* Wzhb  = (unsigned short*)(ws + OFF_WZHB);
  unsigned short* cjb   = (unsigned short*)(ws + OFF_CJB);
  unsigned short* heb   = (unsigned short*)(ws + OFF_HEB);
  float* E              = (float*)(ws + OFF_E);
  unsigned short* gi    = (unsigned short*)(ws + OFF_GI);

  float* out = (float*)d_out;
  float* hn  = out + 16777216;   // T*B*H

  hipFuncSetAttribute((const void*)k_rnn, hipFuncAttributeMaxDynamicSharedMemorySize, 98432);

  hipMemsetAsync(seq, 0, 16384, stream);
  k_cvt_bf16<<<2048, 256, 0, stream>>>(input_, Xb, 16777216 / 4);
  k_cvt_bf16<<<1024, 256, 0, stream>>>(w_ih, Wihb, 3145728 / 4);
  k_cvt_bf16<<<1024, 256, 0, stream>>>(w_hh, Whhb, 3145728 / 4);
  k_cvt_bf16<<<1024, 256, 0, stream>>>(w_ch, Wchb, 3145728 / 4);
  k_cvt_bf16<<<1024, 256, 0, stream>>>(w_zh, Wzhb, 3145728 / 4);
  k_cvt_bf16<<<64, 256, 0, stream>>>(cj, cjb, 65536 / 4);
  k_cvt_bf16<<<64, 256, 0, stream>>>(he, heb, 65536 / 4);
  k_ctx<<<192, 256, 0, stream>>>(cjb, heb, Wchb, Wzhb, b_ih, b_hh, b_ch, b_zh, E);
  k_gemm_gi<<<3072, 256, 0, stream>>>(Xb, Wihb, E, gi);
  k_rnn<<<64, 128, 98432, stream>>>(gi, Whhb, b_hh, h0, length, hbuf, out, hn, seq);
}